// Round 9
// baseline (962.380 us; speedup 1.0000x reference)
//
#include <hip/hip_runtime.h>

// GCN: 3x GCNConv(sym-norm, self-loops) + ReLU, mean-pool per graph, FC.
// Strategy: fold dinv into per-layer G = dinv .* (X@W); build dst-CSR once
// per call so aggregation is atomic-free.
// R1-R7: chased store-coalescing; falsified. True model: WRITE ~= 32B x
//   (# global no-return atomics) + stores; atomics also latency-bound the
//   kernel (~25G/s).
// R8: zero global atomics in CSR build (LDS multisplit + per-bucket k_place)
//   -> 480us; k_agg x3 (195us) now dominates: 410MB logical gather, 187MB
//   L2-miss @ ~3TB/s. G=12.8MB > 4MB/XCD L2 and every XCD touches all of it.
// R9: chunk-per-XCD. G stored [8][NN][4]; agg block b handles chunk b&7 ->
//   each XCD's gathers confined to its own 1.6MB L2-resident chunk. col is
//   re-streamed 8x (102MB) but sequential+nt (L1 gives 16x line reuse).
//   One thread per node, float4 gather, 8-deep ILP.

#define NN 100000
#define EE 3200000
#define FIN 128
#define HID 32
#define NGR 256
#define NC 10
#define NBUK 256
#define BRANGE 391    // 256*391 = 100096 >= NN
#define BSLACK 13400  // mean 12500, sd ~112 -> ~8 sigma slack (input is fixed)
#define TILE 8192

__global__ void k_init(int* __restrict__ bcur) {
  int t = threadIdx.x;
  if (t < NBUK) bcur[t] = t * BSLACK;
}

// Pass A: LDS multisplit of one 8192-edge tile into 256 dst-buckets.
__global__ __launch_bounds__(256) void k_bucket(const int* __restrict__ ei,
                                                int* __restrict__ bcur,
                                                long long* __restrict__ bpair) {
  __shared__ int hist[NBUK];
  __shared__ int bexc[NBUK];
  __shared__ int cnt[NBUK];
  __shared__ int gofs[NBUK];
  __shared__ long long sorted[TILE];  // 64 KB
  int t = threadIdx.x;
  const int* src = ei;
  const int* dst = ei + EE;
  int e0 = blockIdx.x * TILE;
  int tn = EE - e0;
  if (tn > TILE) tn = TILE;

  hist[t] = 0;
  cnt[t] = 0;
  __syncthreads();

  for (int i = t; i < tn; i += 256) {
    int d = __builtin_nontemporal_load(&dst[e0 + i]);
    atomicAdd(&hist[d / BRANGE], 1);
  }
  __syncthreads();

  int hv = hist[t];
  bexc[t] = hv;
  __syncthreads();
#pragma unroll
  for (int off = 1; off < NBUK; off <<= 1) {
    int x = (t >= off) ? bexc[t - off] : 0;
    __syncthreads();
    bexc[t] += x;
    __syncthreads();
  }
  {
    int inc = bexc[t];
    bexc[t] = inc - hv;
    if (hv > 0) gofs[t] = atomicAdd(&bcur[t], hv);  // ~65K atomics total
  }
  __syncthreads();

  for (int i = t; i < tn; i += 256) {
    int d = dst[e0 + i];
    int s = src[e0 + i];
    int q = d / BRANGE;
    int p = bexc[q] + atomicAdd(&cnt[q], 1);
    sorted[p] = ((long long)(unsigned)d << 32) | (unsigned)s;
  }
  __syncthreads();

  for (int i = t; i < tn; i += 256) {
    long long pr = sorted[i];
    int q = (int)(unsigned)(pr >> 32) / BRANGE;
    __builtin_nontemporal_store(pr, &bpair[(size_t)gofs[q] + (i - bexc[q])]);
  }
}

// Fused CSR finalize: one block per bucket, zero global atomics.
__global__ __launch_bounds__(256) void k_place(const long long* __restrict__ bpair,
                                               const int* __restrict__ bcur,
                                               float* __restrict__ dinv,
                                               int* __restrict__ row_ptr,
                                               int* __restrict__ col) {
  __shared__ int bs[NBUK];
  __shared__ int cnt[BRANGE];
  __shared__ int thsum[256];
  int b = blockIdx.x, t = threadIdx.x;

  bs[t] = bcur[t] - t * BSLACK;
  __syncthreads();
#pragma unroll
  for (int off = 1; off < NBUK; off <<= 1) {
    int x = (t >= off) ? bs[t - off] : 0;
    __syncthreads();
    bs[t] += x;
    __syncthreads();
  }
  int sz = bcur[b] - b * BSLACK;
  int colbase = bs[b] - sz;

  for (int i = t; i < BRANGE; i += 256) cnt[i] = 0;
  __syncthreads();

  int lo = b * BRANGE;
  int nnode = NN - lo;
  if (nnode > BRANGE) nnode = BRANGE;
  size_t e0 = (size_t)b * BSLACK;

  for (int i = t; i < sz; i += 256) {
    long long pr = bpair[e0 + i];
    int d = (int)(unsigned)(pr >> 32);
    atomicAdd(&cnt[d - lo], 1);
  }
  __syncthreads();

  int i0 = 2 * t, i1 = 2 * t + 1;
  int v0 = (i0 < BRANGE) ? cnt[i0] : 0;
  int v1 = (i1 < BRANGE) ? cnt[i1] : 0;
  thsum[t] = v0 + v1;
  __syncthreads();
#pragma unroll
  for (int off = 1; off < 256; off <<= 1) {
    int x = (t >= off) ? thsum[t - off] : 0;
    __syncthreads();
    thsum[t] += x;
    __syncthreads();
  }
  int run = thsum[t] - (v0 + v1);
  if (i0 < nnode) {
    row_ptr[lo + i0] = colbase + run;
    dinv[lo + i0] = rsqrtf((float)(v0 + 1));  // +1 = self-loop
  }
  if (i0 < BRANGE) cnt[i0] = colbase + run;
  run += v0;
  if (i1 < nnode) {
    row_ptr[lo + i1] = colbase + run;
    dinv[lo + i1] = rsqrtf((float)(v1 + 1));
  }
  if (i1 < BRANGE) cnt[i1] = colbase + run;
  if (b == NBUK - 1 && t == 0) row_ptr[NN] = EE;
  __syncthreads();

  for (int i = t; i < sz; i += 256) {
    long long pr = bpair[e0 + i];
    int d = (int)(unsigned)(pr >> 32);
    int s = (int)(unsigned)(pr & 0xffffffffLL);
    int pos = atomicAdd(&cnt[d - lo], 1);
    col[pos] = s;
  }
}

// G = dinv .* (X @ W), stored CHUNKED: G[f4][node][4] (f4 = chunk 0..7).
// 128 nodes/block, thread = 4 nodes x 4 feats. xs stride 36 breaks conflicts.
template <int K>
__global__ __launch_bounds__(256) void k_gemm(const float* __restrict__ X,
                                              const float* __restrict__ W,
                                              const float* __restrict__ dinv,
                                              float* __restrict__ Gout) {
  __shared__ float Wl[K * HID];
  __shared__ float xs[128 * 36];
  int t = threadIdx.x;
  for (int i = t; i < K * HID; i += 256) Wl[i] = W[i];
  int node0 = blockIdx.x * 128;
  int ng = t >> 3, f4 = t & 7;
  float acc[4][4];
#pragma unroll
  for (int j = 0; j < 4; j++)
#pragma unroll
    for (int c = 0; c < 4; c++) acc[j][c] = 0.f;

  for (int kc = 0; kc < K; kc += 32) {
    __syncthreads();
#pragma unroll
    for (int j = 0; j < 4; j++) {
      int idx = t + 256 * j;
      int r = idx >> 3, c4 = idx & 7;
      int row = node0 + r;
      if (row >= NN) row = NN - 1;
      float4 v = *reinterpret_cast<const float4*>(&X[(size_t)row * K + kc + c4 * 4]);
      *reinterpret_cast<float4*>(&xs[r * 36 + c4 * 4]) = v;
    }
    __syncthreads();
#pragma unroll
    for (int k4 = 0; k4 < 8; k4++) {
      float4 xv[4];
#pragma unroll
      for (int j = 0; j < 4; j++)
        xv[j] = *reinterpret_cast<const float4*>(&xs[(ng * 4 + j) * 36 + k4 * 4]);
#pragma unroll
      for (int kk = 0; kk < 4; kk++) {
        float4 wv = *reinterpret_cast<const float4*>(&Wl[(kc + k4 * 4 + kk) * HID + f4 * 4]);
#pragma unroll
        for (int j = 0; j < 4; j++) {
          float xvj = (kk == 0) ? xv[j].x : (kk == 1) ? xv[j].y : (kk == 2) ? xv[j].z : xv[j].w;
          acc[j][0] += xvj * wv.x;
          acc[j][1] += xvj * wv.y;
          acc[j][2] += xvj * wv.z;
          acc[j][3] += xvj * wv.w;
        }
      }
    }
  }
#pragma unroll
  for (int j = 0; j < 4; j++) {
    int node = node0 + ng * 4 + j;
    if (node < NN) {
      float s = dinv[node];
      float4 o;
      o.x = acc[j][0] * s;
      o.y = acc[j][1] * s;
      o.z = acc[j][2] * s;
      o.w = acc[j][3] * s;
      reinterpret_cast<float4*>(Gout)[(size_t)f4 * NN + node] = o;  // chunked
    }
  }
}

static __device__ __forceinline__ void add4(float4& a, const float4& b) {
  a.x += b.x; a.y += b.y; a.z += b.z; a.w += b.w;
}

// X'[n] = act(dinv[n] * (sum G[src] + G[n]) + b), feature-chunked:
// block b -> chunk c=b&7 (rides blockIdx%8->XCD round-robin so each XCD's
// gathers stay inside its own 1.6MB L2-resident chunk). 1 thread = 1 node,
// float4 gather, 8 independent accumulators. col nt (don't evict chunk).
__global__ __launch_bounds__(256) void k_agg(const float* __restrict__ Gin,
                                             const int* __restrict__ col,
                                             const int* __restrict__ row_ptr,
                                             const float* __restrict__ dinv,
                                             const float* __restrict__ bias,
                                             float* __restrict__ Xout, int relu) {
  const float4* G4 = reinterpret_cast<const float4*>(Gin);
  int c = blockIdx.x & 7;
  int n = (blockIdx.x >> 3) * 256 + threadIdx.x;
  if (n >= NN) return;
  int beg = row_ptr[n], end = row_ptr[n + 1];
  size_t cb = (size_t)c * NN;

  float4 a0 = G4[cb + n];  // self-loop term
  float4 a1 = {0, 0, 0, 0}, a2 = {0, 0, 0, 0}, a3 = {0, 0, 0, 0};
  float4 a4 = {0, 0, 0, 0}, a5 = {0, 0, 0, 0}, a6 = {0, 0, 0, 0}, a7 = {0, 0, 0, 0};

  int i = beg;
  for (; i + 8 <= end; i += 8) {
    int s0 = __builtin_nontemporal_load(&col[i + 0]);
    int s1 = __builtin_nontemporal_load(&col[i + 1]);
    int s2 = __builtin_nontemporal_load(&col[i + 2]);
    int s3 = __builtin_nontemporal_load(&col[i + 3]);
    int s4 = __builtin_nontemporal_load(&col[i + 4]);
    int s5 = __builtin_nontemporal_load(&col[i + 5]);
    int s6 = __builtin_nontemporal_load(&col[i + 6]);
    int s7 = __builtin_nontemporal_load(&col[i + 7]);
    float4 g0 = G4[cb + s0];
    float4 g1 = G4[cb + s1];
    float4 g2 = G4[cb + s2];
    float4 g3 = G4[cb + s3];
    float4 g4 = G4[cb + s4];
    float4 g5 = G4[cb + s5];
    float4 g6 = G4[cb + s6];
    float4 g7 = G4[cb + s7];
    add4(a0, g0); add4(a1, g1); add4(a2, g2); add4(a3, g3);
    add4(a4, g4); add4(a5, g5); add4(a6, g6); add4(a7, g7);
  }
  for (; i < end; i++) {
    int s = __builtin_nontemporal_load(&col[i]);
    float4 g = G4[cb + s];
    add4(a0, g);
  }
  add4(a0, a1); add4(a2, a3); add4(a4, a5); add4(a6, a7);
  add4(a0, a2); add4(a4, a6); add4(a0, a4);

  float s = dinv[n];
  float4 b = reinterpret_cast<const float4*>(bias)[c];
  float4 v;
  v.x = s * a0.x + b.x;
  v.y = s * a0.y + b.y;
  v.z = s * a0.z + b.z;
  v.w = s * a0.w + b.w;
  if (relu) {
    v.x = fmaxf(v.x, 0.f);
    v.y = fmaxf(v.y, 0.f);
    v.z = fmaxf(v.z, 0.f);
    v.w = fmaxf(v.w, 0.f);
  }
  reinterpret_cast<float4*>(Xout)[(size_t)n * 8 + c] = v;  // standard [n][32]
}

// Mean-pool: batch is sorted, so flush-on-graph-change keeps atomics rare.
__global__ __launch_bounds__(256) void k_pool(const float* __restrict__ X,
                                              const int* __restrict__ batch,
                                              float* __restrict__ sums,
                                              int* __restrict__ counts) {
  int t = threadIdx.x;
  int f = t & 31, slot = t >> 5;
  int base = blockIdx.x * 512;
  float acc = 0.f;
  int cnt = 0, cur = -1;
  for (int i = 0; i < 64; i++) {
    int n = base + slot + i * 8;
    if (n >= NN) break;
    int g = batch[n];
    if (g != cur) {
      if (cur >= 0) {
        atomicAdd(&sums[cur * HID + f], acc);
        if (f == 0) atomicAdd(&counts[cur], cnt);
      }
      cur = g;
      acc = 0.f;
      cnt = 0;
    }
    acc += X[(size_t)n * HID + f];
    cnt++;
  }
  if (cur >= 0) {
    atomicAdd(&sums[cur * HID + f], acc);
    if (f == 0) atomicAdd(&counts[cur], cnt);
  }
}

__global__ void k_fc(const float* __restrict__ sums, const int* __restrict__ counts,
                     const float* __restrict__ Wfc, const float* __restrict__ bfc,
                     float* __restrict__ out) {
  int idx = blockIdx.x * 256 + threadIdx.x;
  if (idx >= NGR * NC) return;
  int g = idx / NC, c = idx % NC;
  float inv = 1.f / fmaxf((float)counts[g], 1.f);
  float acc = bfc[c];
#pragma unroll
  for (int k = 0; k < HID; k++) acc += sums[g * HID + k] * inv * Wfc[k * NC + c];
  out[idx] = acc;
}

extern "C" void kernel_launch(void* const* d_in, const int* in_sizes, int n_in,
                              void* d_out, int out_size, void* d_ws, size_t ws_size,
                              hipStream_t stream) {
  (void)in_sizes; (void)n_in; (void)out_size; (void)ws_size;
  const float* x = (const float*)d_in[0];
  const int* ei = (const int*)d_in[1];
  const int* batch = (const int*)d_in[2];
  const float* W1 = (const float*)d_in[3];
  const float* b1 = (const float*)d_in[4];
  const float* W2 = (const float*)d_in[5];
  const float* b2 = (const float*)d_in[6];
  const float* W3 = (const float*)d_in[7];
  const float* b3 = (const float*)d_in[8];
  const float* Wfc = (const float*)d_in[9];
  const float* bfc = (const float*)d_in[10];
  float* out = (float*)d_out;

  char* ws = (char*)d_ws;
  size_t off = 0;
  auto alloc = [&](size_t bytes) -> void* {
    void* p = ws + off;
    off = (off + bytes + 255) & ~(size_t)255;
    return p;
  };
  float* dinv = (float*)alloc((size_t)NN * 4);
  int* row_ptr = (int*)alloc((size_t)(NN + 1) * 4);
  int* bcur = (int*)alloc(NBUK * 4);
  int* col = (int*)alloc((size_t)EE * 4);
  // Union region: bpair (CSR build only) overlaps Gbuf+Abuf (GEMM phase only).
  size_t bpair_bytes = (size_t)NBUK * BSLACK * 8;       // 27.4 MB
  size_t gbuf_bytes = (size_t)NN * HID * 4;             // 12.8 MB
  char* uni = (char*)alloc(bpair_bytes > 2 * gbuf_bytes ? bpair_bytes : 2 * gbuf_bytes);
  long long* bpair = (long long*)uni;
  float* Gbuf = (float*)uni;
  float* Abuf = (float*)(uni + gbuf_bytes);
  float* sums = (float*)alloc((size_t)NGR * HID * 4);
  int* counts = (int*)alloc((size_t)NGR * 4);

  hipMemsetAsync(sums, 0, (size_t)NGR * HID * 4, stream);
  hipMemsetAsync(counts, 0, (size_t)NGR * 4, stream);

  k_init<<<1, NBUK, 0, stream>>>(bcur);
  k_bucket<<<(EE + TILE - 1) / TILE, 256, 0, stream>>>(ei, bcur, bpair);
  k_place<<<NBUK, 256, 0, stream>>>(bpair, bcur, dinv, row_ptr, col);

  int nba = (NN + 255) / 256;  // 391 node-blocks per chunk
  k_gemm<FIN><<<(NN + 127) / 128, 256, 0, stream>>>(x, W1, dinv, Gbuf);
  k_agg<<<nba * 8, 256, 0, stream>>>(Gbuf, col, row_ptr, dinv, b1, Abuf, 1);
  k_gemm<HID><<<(NN + 127) / 128, 256, 0, stream>>>(Abuf, W2, dinv, Gbuf);
  k_agg<<<nba * 8, 256, 0, stream>>>(Gbuf, col, row_ptr, dinv, b2, Abuf, 1);
  k_gemm<HID><<<(NN + 127) / 128, 256, 0, stream>>>(Abuf, W3, dinv, Gbuf);
  k_agg<<<nba * 8, 256, 0, stream>>>(Gbuf, col, row_ptr, dinv, b3, Abuf, 0);

  k_pool<<<(NN + 511) / 512, 256, 0, stream>>>(Abuf, batch, sums, counts);
  k_fc<<<(NGR * NC + 255) / 256, 256, 0, stream>>>(sums, counts, Wfc, bfc, out);
}

// Round 10
// 437.646 us; speedup vs baseline: 2.1990x; 2.1990x over previous
//
#include <hip/hip_runtime.h>

// GCN: 3x GCNConv(sym-norm, self-loops) + ReLU, mean-pool per graph, FC.
// Strategy: fold dinv into per-layer G = dinv .* (X@W); build dst-CSR once
// per call so aggregation is atomic-free.
// R1-R7: chased store-coalescing; falsified. True model: WRITE ~= 32B x
//   (# global no-return atomics) + stores; atomics also latency-bound.
// R8: zero global atomics in CSR build -> 480us; k_agg x3 (195us) dominates:
//   410MB logical gather, 187MB L2-miss fills.
// R9: chunk-per-XCD G layout FAILED (229us/agg, FETCH 320MB): chunks not
//   L2-retained + 8x col re-stream + 8x instruction count. Reverted.
// R10: R8 agg structure, but G stored fp16: row = 64B = ONE aligned line
//   per edge gather (was two), logical 205MB. Error budget fine (G~0.2 std,
//   eps 5e-4 -> ~1e-4/layer vs 1.97e-3 threshold).

#include <hip/hip_fp16.h>

#define NN 100000
#define EE 3200000
#define FIN 128
#define HID 32
#define NGR 256
#define NC 10
#define NBUK 256
#define BRANGE 391    // 256*391 = 100096 >= NN
#define BSLACK 13400  // mean 12500, sd ~112 -> ~8 sigma slack (input is fixed)
#define TILE 8192

typedef _Float16 h2 __attribute__((ext_vector_type(2)));
typedef _Float16 h4 __attribute__((ext_vector_type(4)));

__global__ void k_init(int* __restrict__ bcur) {
  int t = threadIdx.x;
  if (t < NBUK) bcur[t] = t * BSLACK;
}

// Pass A: LDS multisplit of one 8192-edge tile into 256 dst-buckets.
__global__ __launch_bounds__(256) void k_bucket(const int* __restrict__ ei,
                                                int* __restrict__ bcur,
                                                long long* __restrict__ bpair) {
  __shared__ int hist[NBUK];
  __shared__ int bexc[NBUK];
  __shared__ int cnt[NBUK];
  __shared__ int gofs[NBUK];
  __shared__ long long sorted[TILE];  // 64 KB
  int t = threadIdx.x;
  const int* src = ei;
  const int* dst = ei + EE;
  int e0 = blockIdx.x * TILE;
  int tn = EE - e0;
  if (tn > TILE) tn = TILE;

  hist[t] = 0;
  cnt[t] = 0;
  __syncthreads();

  for (int i = t; i < tn; i += 256) {
    int d = __builtin_nontemporal_load(&dst[e0 + i]);
    atomicAdd(&hist[d / BRANGE], 1);
  }
  __syncthreads();

  int hv = hist[t];
  bexc[t] = hv;
  __syncthreads();
#pragma unroll
  for (int off = 1; off < NBUK; off <<= 1) {
    int x = (t >= off) ? bexc[t - off] : 0;
    __syncthreads();
    bexc[t] += x;
    __syncthreads();
  }
  {
    int inc = bexc[t];
    bexc[t] = inc - hv;
    if (hv > 0) gofs[t] = atomicAdd(&bcur[t], hv);  // ~65K atomics total
  }
  __syncthreads();

  for (int i = t; i < tn; i += 256) {
    int d = dst[e0 + i];
    int s = src[e0 + i];
    int q = d / BRANGE;
    int p = bexc[q] + atomicAdd(&cnt[q], 1);
    sorted[p] = ((long long)(unsigned)d << 32) | (unsigned)s;
  }
  __syncthreads();

  for (int i = t; i < tn; i += 256) {
    long long pr = sorted[i];
    int q = (int)(unsigned)(pr >> 32) / BRANGE;
    __builtin_nontemporal_store(pr, &bpair[(size_t)gofs[q] + (i - bexc[q])]);
  }
}

// Fused CSR finalize: one block per bucket, zero global atomics.
__global__ __launch_bounds__(256) void k_place(const long long* __restrict__ bpair,
                                               const int* __restrict__ bcur,
                                               float* __restrict__ dinv,
                                               int* __restrict__ row_ptr,
                                               int* __restrict__ col) {
  __shared__ int bs[NBUK];
  __shared__ int cnt[BRANGE];
  __shared__ int thsum[256];
  int b = blockIdx.x, t = threadIdx.x;

  bs[t] = bcur[t] - t * BSLACK;
  __syncthreads();
#pragma unroll
  for (int off = 1; off < NBUK; off <<= 1) {
    int x = (t >= off) ? bs[t - off] : 0;
    __syncthreads();
    bs[t] += x;
    __syncthreads();
  }
  int sz = bcur[b] - b * BSLACK;
  int colbase = bs[b] - sz;

  for (int i = t; i < BRANGE; i += 256) cnt[i] = 0;
  __syncthreads();

  int lo = b * BRANGE;
  int nnode = NN - lo;
  if (nnode > BRANGE) nnode = BRANGE;
  size_t e0 = (size_t)b * BSLACK;

  for (int i = t; i < sz; i += 256) {
    long long pr = bpair[e0 + i];
    int d = (int)(unsigned)(pr >> 32);
    atomicAdd(&cnt[d - lo], 1);
  }
  __syncthreads();

  int i0 = 2 * t, i1 = 2 * t + 1;
  int v0 = (i0 < BRANGE) ? cnt[i0] : 0;
  int v1 = (i1 < BRANGE) ? cnt[i1] : 0;
  thsum[t] = v0 + v1;
  __syncthreads();
#pragma unroll
  for (int off = 1; off < 256; off <<= 1) {
    int x = (t >= off) ? thsum[t - off] : 0;
    __syncthreads();
    thsum[t] += x;
    __syncthreads();
  }
  int run = thsum[t] - (v0 + v1);
  if (i0 < nnode) {
    row_ptr[lo + i0] = colbase + run;
    dinv[lo + i0] = rsqrtf((float)(v0 + 1));  // +1 = self-loop
  }
  if (i0 < BRANGE) cnt[i0] = colbase + run;
  run += v0;
  if (i1 < nnode) {
    row_ptr[lo + i1] = colbase + run;
    dinv[lo + i1] = rsqrtf((float)(v1 + 1));
  }
  if (i1 < BRANGE) cnt[i1] = colbase + run;
  if (b == NBUK - 1 && t == 0) row_ptr[NN] = EE;
  __syncthreads();

  for (int i = t; i < sz; i += 256) {
    long long pr = bpair[e0 + i];
    int d = (int)(unsigned)(pr >> 32);
    int s = (int)(unsigned)(pr & 0xffffffffLL);
    int pos = atomicAdd(&cnt[d - lo], 1);
    col[pos] = s;
  }
}

// G = dinv .* (X @ W), stored fp16 [node][32] (64B rows = 1 cache line).
// 128 nodes/block, thread = 4 nodes x 4 feats. xs stride 36 breaks conflicts.
template <int K>
__global__ __launch_bounds__(256) void k_gemm(const float* __restrict__ X,
                                              const float* __restrict__ W,
                                              const float* __restrict__ dinv,
                                              _Float16* __restrict__ Gout) {
  __shared__ float Wl[K * HID];
  __shared__ float xs[128 * 36];
  int t = threadIdx.x;
  for (int i = t; i < K * HID; i += 256) Wl[i] = W[i];
  int node0 = blockIdx.x * 128;
  int ng = t >> 3, f4 = t & 7;
  float acc[4][4];
#pragma unroll
  for (int j = 0; j < 4; j++)
#pragma unroll
    for (int c = 0; c < 4; c++) acc[j][c] = 0.f;

  for (int kc = 0; kc < K; kc += 32) {
    __syncthreads();
#pragma unroll
    for (int j = 0; j < 4; j++) {
      int idx = t + 256 * j;
      int r = idx >> 3, c4 = idx & 7;
      int row = node0 + r;
      if (row >= NN) row = NN - 1;
      float4 v = *reinterpret_cast<const float4*>(&X[(size_t)row * K + kc + c4 * 4]);
      *reinterpret_cast<float4*>(&xs[r * 36 + c4 * 4]) = v;
    }
    __syncthreads();
#pragma unroll
    for (int k4 = 0; k4 < 8; k4++) {
      float4 xv[4];
#pragma unroll
      for (int j = 0; j < 4; j++)
        xv[j] = *reinterpret_cast<const float4*>(&xs[(ng * 4 + j) * 36 + k4 * 4]);
#pragma unroll
      for (int kk = 0; kk < 4; kk++) {
        float4 wv = *reinterpret_cast<const float4*>(&Wl[(kc + k4 * 4 + kk) * HID + f4 * 4]);
#pragma unroll
        for (int j = 0; j < 4; j++) {
          float xvj = (kk == 0) ? xv[j].x : (kk == 1) ? xv[j].y : (kk == 2) ? xv[j].z : xv[j].w;
          acc[j][0] += xvj * wv.x;
          acc[j][1] += xvj * wv.y;
          acc[j][2] += xvj * wv.z;
          acc[j][3] += xvj * wv.w;
        }
      }
    }
  }
#pragma unroll
  for (int j = 0; j < 4; j++) {
    int node = node0 + ng * 4 + j;
    if (node < NN) {
      float s = dinv[node];
      h4 o;
      o.x = (_Float16)(acc[j][0] * s);
      o.y = (_Float16)(acc[j][1] * s);
      o.z = (_Float16)(acc[j][2] * s);
      o.w = (_Float16)(acc[j][3] * s);
      reinterpret_cast<h4*>(Gout)[(size_t)node * 8 + f4] = o;
    }
  }
}

// X'[n] = act(dinv[n] * (sum G[src] + G[n]) + b). G fp16: 16 lanes x h2
// (4B/lane, 64B/row = one line per edge gather). 16 nodes/block; 8x unroll
// into 8 independent accumulators for 8 outstanding gathers per slot.
__global__ __launch_bounds__(256) void k_agg(const _Float16* __restrict__ Gin,
                                             const int* __restrict__ col,
                                             const int* __restrict__ row_ptr,
                                             const float* __restrict__ dinv,
                                             const float* __restrict__ bias,
                                             float* __restrict__ Xout, int relu) {
  const h2* G2 = reinterpret_cast<const h2*>(Gin);
  int t = threadIdx.x;
  int h = t & 15;          // h2 index within row (feats 2h, 2h+1)
  int slot = t >> 4;       // 0..15 node slot within block
  int n = blockIdx.x * 16 + slot;
  int beg = row_ptr[n], end = row_ptr[n + 1];

  h2 g0 = G2[(size_t)n * 16 + h];  // self-loop term
  float ax0 = (float)g0.x, ay0 = (float)g0.y;
  float ax1 = 0.f, ay1 = 0.f, ax2 = 0.f, ay2 = 0.f, ax3 = 0.f, ay3 = 0.f;
  float ax4 = 0.f, ay4 = 0.f, ax5 = 0.f, ay5 = 0.f, ax6 = 0.f, ay6 = 0.f;
  float ax7 = 0.f, ay7 = 0.f;

  int i = beg;
  for (; i + 8 <= end; i += 8) {
    int s0 = __builtin_nontemporal_load(&col[i + 0]);
    int s1 = __builtin_nontemporal_load(&col[i + 1]);
    int s2 = __builtin_nontemporal_load(&col[i + 2]);
    int s3 = __builtin_nontemporal_load(&col[i + 3]);
    int s4 = __builtin_nontemporal_load(&col[i + 4]);
    int s5 = __builtin_nontemporal_load(&col[i + 5]);
    int s6 = __builtin_nontemporal_load(&col[i + 6]);
    int s7 = __builtin_nontemporal_load(&col[i + 7]);
    h2 v0 = G2[(size_t)s0 * 16 + h];
    h2 v1 = G2[(size_t)s1 * 16 + h];
    h2 v2 = G2[(size_t)s2 * 16 + h];
    h2 v3 = G2[(size_t)s3 * 16 + h];
    h2 v4 = G2[(size_t)s4 * 16 + h];
    h2 v5 = G2[(size_t)s5 * 16 + h];
    h2 v6 = G2[(size_t)s6 * 16 + h];
    h2 v7 = G2[(size_t)s7 * 16 + h];
    ax0 += (float)v0.x; ay0 += (float)v0.y;
    ax1 += (float)v1.x; ay1 += (float)v1.y;
    ax2 += (float)v2.x; ay2 += (float)v2.y;
    ax3 += (float)v3.x; ay3 += (float)v3.y;
    ax4 += (float)v4.x; ay4 += (float)v4.y;
    ax5 += (float)v5.x; ay5 += (float)v5.y;
    ax6 += (float)v6.x; ay6 += (float)v6.y;
    ax7 += (float)v7.x; ay7 += (float)v7.y;
  }
  for (; i < end; i++) {
    int s = __builtin_nontemporal_load(&col[i]);
    h2 v = G2[(size_t)s * 16 + h];
    ax0 += (float)v.x; ay0 += (float)v.y;
  }
  ax0 += ax1 + ax2 + ax3 + ax4 + ax5 + ax6 + ax7;
  ay0 += ay1 + ay2 + ay3 + ay4 + ay5 + ay6 + ay7;

  float s = dinv[n];
  float2 b = reinterpret_cast<const float2*>(bias)[h];
  float2 v;
  v.x = s * ax0 + b.x;
  v.y = s * ay0 + b.y;
  if (relu) {
    v.x = fmaxf(v.x, 0.f);
    v.y = fmaxf(v.y, 0.f);
  }
  reinterpret_cast<float2*>(Xout)[(size_t)n * 16 + h] = v;
}

// Mean-pool: batch is sorted, so flush-on-graph-change keeps atomics rare.
__global__ __launch_bounds__(256) void k_pool(const float* __restrict__ X,
                                              const int* __restrict__ batch,
                                              float* __restrict__ sums,
                                              int* __restrict__ counts) {
  int t = threadIdx.x;
  int f = t & 31, slot = t >> 5;
  int base = blockIdx.x * 512;
  float acc = 0.f;
  int cnt = 0, cur = -1;
  for (int i = 0; i < 64; i++) {
    int n = base + slot + i * 8;
    if (n >= NN) break;
    int g = batch[n];
    if (g != cur) {
      if (cur >= 0) {
        atomicAdd(&sums[cur * HID + f], acc);
        if (f == 0) atomicAdd(&counts[cur], cnt);
      }
      cur = g;
      acc = 0.f;
      cnt = 0;
    }
    acc += X[(size_t)n * HID + f];
    cnt++;
  }
  if (cur >= 0) {
    atomicAdd(&sums[cur * HID + f], acc);
    if (f == 0) atomicAdd(&counts[cur], cnt);
  }
}

__global__ void k_fc(const float* __restrict__ sums, const int* __restrict__ counts,
                     const float* __restrict__ Wfc, const float* __restrict__ bfc,
                     float* __restrict__ out) {
  int idx = blockIdx.x * 256 + threadIdx.x;
  if (idx >= NGR * NC) return;
  int g = idx / NC, c = idx % NC;
  float inv = 1.f / fmaxf((float)counts[g], 1.f);
  float acc = bfc[c];
#pragma unroll
  for (int k = 0; k < HID; k++) acc += sums[g * HID + k] * inv * Wfc[k * NC + c];
  out[idx] = acc;
}

extern "C" void kernel_launch(void* const* d_in, const int* in_sizes, int n_in,
                              void* d_out, int out_size, void* d_ws, size_t ws_size,
                              hipStream_t stream) {
  (void)in_sizes; (void)n_in; (void)out_size; (void)ws_size;
  const float* x = (const float*)d_in[0];
  const int* ei = (const int*)d_in[1];
  const int* batch = (const int*)d_in[2];
  const float* W1 = (const float*)d_in[3];
  const float* b1 = (const float*)d_in[4];
  const float* W2 = (const float*)d_in[5];
  const float* b2 = (const float*)d_in[6];
  const float* W3 = (const float*)d_in[7];
  const float* b3 = (const float*)d_in[8];
  const float* Wfc = (const float*)d_in[9];
  const float* bfc = (const float*)d_in[10];
  float* out = (float*)d_out;

  char* ws = (char*)d_ws;
  size_t off = 0;
  auto alloc = [&](size_t bytes) -> void* {
    void* p = ws + off;
    off = (off + bytes + 255) & ~(size_t)255;
    return p;
  };
  float* dinv = (float*)alloc((size_t)NN * 4);
  int* row_ptr = (int*)alloc((size_t)(NN + 1) * 4);
  int* bcur = (int*)alloc(NBUK * 4);
  int* col = (int*)alloc((size_t)EE * 4);
  // Union region: bpair (CSR build only) overlaps Gbuf+Abuf (GEMM phase only).
  size_t bpair_bytes = (size_t)NBUK * BSLACK * 8;          // 27.4 MB
  size_t gbuf_bytes = (size_t)NN * HID * 2;                // 6.4 MB (fp16)
  size_t abuf_bytes = (size_t)NN * HID * 4;                // 12.8 MB (fp32)
  size_t need = gbuf_bytes + abuf_bytes;
  char* uni = (char*)alloc(bpair_bytes > need ? bpair_bytes : need);
  long long* bpair = (long long*)uni;
  _Float16* Gbuf = (_Float16*)uni;
  float* Abuf = (float*)(uni + gbuf_bytes);
  float* sums = (float*)alloc((size_t)NGR * HID * 4);
  int* counts = (int*)alloc((size_t)NGR * 4);

  hipMemsetAsync(sums, 0, (size_t)NGR * HID * 4, stream);
  hipMemsetAsync(counts, 0, (size_t)NGR * 4, stream);

  k_init<<<1, NBUK, 0, stream>>>(bcur);
  k_bucket<<<(EE + TILE - 1) / TILE, 256, 0, stream>>>(ei, bcur, bpair);
  k_place<<<NBUK, 256, 0, stream>>>(bpair, bcur, dinv, row_ptr, col);

  k_gemm<FIN><<<(NN + 127) / 128, 256, 0, stream>>>(x, W1, dinv, Gbuf);
  k_agg<<<NN / 16, 256, 0, stream>>>(Gbuf, col, row_ptr, dinv, b1, Abuf, 1);
  k_gemm<HID><<<(NN + 127) / 128, 256, 0, stream>>>(Abuf, W2, dinv, Gbuf);
  k_agg<<<NN / 16, 256, 0, stream>>>(Gbuf, col, row_ptr, dinv, b2, Abuf, 1);
  k_gemm<HID><<<(NN + 127) / 128, 256, 0, stream>>>(Abuf, W3, dinv, Gbuf);
  k_agg<<<NN / 16, 256, 0, stream>>>(Gbuf, col, row_ptr, dinv, b3, Abuf, 0);

  k_pool<<<(NN + 511) / 512, 256, 0, stream>>>(Abuf, batch, sums, counts);
  k_fc<<<(NGR * NC + 255) / 256, 256, 0, stream>>>(sums, counts, Wfc, bfc, out);
}